// Round 1
// baseline (469.668 us; speedup 1.0000x reference)
//
#include <hip/hip_runtime.h>

typedef __bf16 bf16;
typedef __bf16 bf16x8 __attribute__((ext_vector_type(8)));
typedef float f32x4 __attribute__((ext_vector_type(4)));

#define MFMA_BF16(A, B, C) __builtin_amdgcn_mfma_f32_16x16x32_bf16((A), (B), (C), 0, 0, 0)

#define EMB 1024
#define ODIM 2048
#define SEQ 2048
#define HEADS 16
#define HD 128

// ---------------- mask bit-pack: mask (1,S,S) int32 -> mb[q][kt] uint64 ----------------
__global__ __launch_bounds__(256) void build_maskbits_k(const int* __restrict__ mask,
                                                        unsigned long long* __restrict__ mb) {
  int w = blockIdx.x * 256 + threadIdx.x;  // 0..65535 : q*32 + chunk
  int q = w >> 5, c = w & 31;
  const int4* m4 = reinterpret_cast<const int4*>(mask + (size_t)q * SEQ + c * 64);
  unsigned long long bits = 0ull;
#pragma unroll
  for (int i = 0; i < 16; ++i) {
    int4 v = m4[i];
    if (v.x) bits |= 1ull << (i * 4 + 0);
    if (v.y) bits |= 1ull << (i * 4 + 1);
    if (v.z) bits |= 1ull << (i * 4 + 2);
    if (v.w) bits |= 1ull << (i * 4 + 3);
  }
  mb[w] = bits;
}

// ---------------- projection GEMM: out = relu(X (4096x1024) * W^T (2048x1024) + b) ----------------
// vmode==0: write bf16 to outN[row][col] (row-major 4096x2048)
// vmode==1: write bf16 transposed per head to outT[((n*16+h)*128+d)*2048 + s]
__global__ __launch_bounds__(256) void proj_gemm_k(const float* __restrict__ X,
                                                   const float* __restrict__ W,
                                                   const float* __restrict__ bias,
                                                   bf16* __restrict__ outN,
                                                   bf16* __restrict__ outT,
                                                   int vmode) {
  __shared__ union {
    struct { bf16 A[128][40]; bf16 B[128][40]; } s;  // +8 pad: row stride 80B, 2-way max
    bf16 C[128][136];                                // transpose buffer (epilogue only)
  } sm;

  const int t = threadIdx.x;
  const int lane = t & 63;
  const int wid = t >> 6;
  const int wm = wid >> 1, wn = wid & 1;
  const int lr = lane & 15, lg = lane >> 4;
  const int m0 = blockIdx.y * 128;
  const int n0 = blockIdx.x * 128;
  const int sr = t >> 1, sh = (t & 1) * 16;  // staging: 2 threads per row, 16 f32 each

  const f32x4 fzero = {0.f, 0.f, 0.f, 0.f};
  f32x4 acc[4][4];
#pragma unroll
  for (int i = 0; i < 4; ++i)
#pragma unroll
    for (int j = 0; j < 4; ++j) acc[i][j] = fzero;

  const float* Xr = X + (size_t)(m0 + sr) * EMB + sh;
  const float* Wr = W + (size_t)(n0 + sr) * EMB + sh;

  for (int k0 = 0; k0 < EMB; k0 += 32) {
    {
      const float4* pa = reinterpret_cast<const float4*>(Xr + k0);
      const float4* pb = reinterpret_cast<const float4*>(Wr + k0);
      float4 a0 = pa[0], a1 = pa[1], a2 = pa[2], a3 = pa[3];
      float4 b0 = pb[0], b1 = pb[1], b2 = pb[2], b3 = pb[3];
      bf16x8 v0, v1, w0, w1;
      v0[0] = (bf16)a0.x; v0[1] = (bf16)a0.y; v0[2] = (bf16)a0.z; v0[3] = (bf16)a0.w;
      v0[4] = (bf16)a1.x; v0[5] = (bf16)a1.y; v0[6] = (bf16)a1.z; v0[7] = (bf16)a1.w;
      v1[0] = (bf16)a2.x; v1[1] = (bf16)a2.y; v1[2] = (bf16)a2.z; v1[3] = (bf16)a2.w;
      v1[4] = (bf16)a3.x; v1[5] = (bf16)a3.y; v1[6] = (bf16)a3.z; v1[7] = (bf16)a3.w;
      w0[0] = (bf16)b0.x; w0[1] = (bf16)b0.y; w0[2] = (bf16)b0.z; w0[3] = (bf16)b0.w;
      w0[4] = (bf16)b1.x; w0[5] = (bf16)b1.y; w0[6] = (bf16)b1.z; w0[7] = (bf16)b1.w;
      w1[0] = (bf16)b2.x; w1[1] = (bf16)b2.y; w1[2] = (bf16)b2.z; w1[3] = (bf16)b2.w;
      w1[4] = (bf16)b3.x; w1[5] = (bf16)b3.y; w1[6] = (bf16)b3.z; w1[7] = (bf16)b3.w;
      *(bf16x8*)&sm.s.A[sr][sh] = v0;
      *(bf16x8*)&sm.s.A[sr][sh + 8] = v1;
      *(bf16x8*)&sm.s.B[sr][sh] = w0;
      *(bf16x8*)&sm.s.B[sr][sh + 8] = w1;
    }
    __syncthreads();
    bf16x8 af[4], bfr[4];
#pragma unroll
    for (int i = 0; i < 4; ++i) af[i] = *(const bf16x8*)&sm.s.A[wm * 64 + i * 16 + lr][lg * 8];
#pragma unroll
    for (int i = 0; i < 4; ++i) bfr[i] = *(const bf16x8*)&sm.s.B[wn * 64 + i * 16 + lr][lg * 8];
#pragma unroll
    for (int mi = 0; mi < 4; ++mi)
#pragma unroll
      for (int ni = 0; ni < 4; ++ni)
        acc[mi][ni] = MFMA_BF16(af[mi], bfr[ni], acc[mi][ni]);
    __syncthreads();
  }

  float bv_[4];
#pragma unroll
  for (int ni = 0; ni < 4; ++ni) bv_[ni] = bias[n0 + wn * 64 + ni * 16 + lr];

  if (!vmode) {
#pragma unroll
    for (int mi = 0; mi < 4; ++mi)
#pragma unroll
      for (int ni = 0; ni < 4; ++ni)
#pragma unroll
        for (int j = 0; j < 4; ++j) {
          float v = fmaxf(acc[mi][ni][j] + bv_[ni], 0.f);
          int row = m0 + wm * 64 + mi * 16 + lg * 4 + j;
          int col = n0 + wn * 64 + ni * 16 + lr;
          outN[(size_t)row * ODIM + col] = (bf16)v;
        }
  } else {
    // transpose tile through LDS, then coalesced row writes into Vt[n][h][d][s]
#pragma unroll
    for (int mi = 0; mi < 4; ++mi)
#pragma unroll
      for (int ni = 0; ni < 4; ++ni)
#pragma unroll
        for (int j = 0; j < 4; ++j) {
          float v = fmaxf(acc[mi][ni][j] + bv_[ni], 0.f);
          int rit = wm * 64 + mi * 16 + lg * 4 + j;  // s within tile
          int cit = wn * 64 + ni * 16 + lr;          // d within tile
          sm.C[cit][rit] = (bf16)v;
        }
    __syncthreads();
    const int n = m0 >> 11;
    const int s0 = m0 & (SEQ - 1);
    const int h = blockIdx.x;  // n0/128 == head (BN==HD)
    bf16* base = outT + ((size_t)(n * HEADS + h) * HD) * SEQ + s0;
#pragma unroll
    for (int i = 0; i < 8; ++i) {
      int cid = i * 256 + t;
      int d = cid >> 4, c = cid & 15;
      *(bf16x8*)(base + (size_t)d * SEQ + c * 8) = *(const bf16x8*)&sm.C[d][c * 8];
    }
  }
}

// ---------------- flash attention ----------------
// grid: x = q-tile (S/64), y = n*16+h ; 256 threads = 4 waves, 16 q-rows per wave
__global__ __launch_bounds__(256) void attn_k(const bf16* __restrict__ Qb,
                                              const bf16* __restrict__ Kb,
                                              const bf16* __restrict__ Vt,
                                              const unsigned long long* __restrict__ mb,
                                              float* __restrict__ out) {
  __shared__ bf16 Ks[64][136];    // K tile: [key][d], +8 pad -> 2-way conflicts max
  __shared__ bf16 Vs[128][72];    // V^T tile: [d][s], +8 pad
  __shared__ bf16 Ps[4][16][72];  // per-wave P: [qrow][key], +8 pad

  const int t = threadIdx.x;
  const int lane = t & 63;
  const int w = t >> 6;
  const int lr = lane & 15, lg = lane >> 4;
  const int nh = blockIdx.y;
  const int n = nh >> 4, h = nh & 15;
  const int q0 = blockIdx.x * 64;
  const int qrow = q0 + w * 16;

  // Q fragments (held for whole kernel): A-frag row = lane&15
  bf16x8 qf[4];
  {
    const bf16* qp = Qb + (size_t)(n * SEQ + qrow + lr) * ODIM + h * HD + lg * 8;
#pragma unroll
    for (int ks = 0; ks < 4; ++ks) qf[ks] = *(const bf16x8*)(qp + ks * 32);
  }

  const f32x4 fzero = {0.f, 0.f, 0.f, 0.f};
  f32x4 oacc[8];
#pragma unroll
  for (int i = 0; i < 8; ++i) oacc[i] = fzero;
  float mrun[4], lrun[4];
#pragma unroll
  for (int j = 0; j < 4; ++j) { mrun[j] = -3.0e38f; lrun[j] = 0.f; }

  const bf16* Kg = Kb + (size_t)(n * SEQ) * ODIM + h * HD;
  const bf16* Vg = Vt + (size_t)nh * HD * SEQ;

  const float scale = 0.08838834764831845f;  // 1/sqrt(128)
  const float L2E = 1.4426950408889634f;

  for (int kt = 0; kt < SEQ / 64; ++kt) {
    // ---- stage K (64x128) and V^T (128x64) ----
#pragma unroll
    for (int i = 0; i < 4; ++i) {
      int cid = i * 256 + t;
      int r = cid >> 4, c = cid & 15;
      *(bf16x8*)&Ks[r][c * 8] = *(const bf16x8*)(Kg + (size_t)(kt * 64 + r) * ODIM + c * 8);
    }
#pragma unroll
    for (int i = 0; i < 4; ++i) {
      int cid = i * 256 + t;
      int d = cid >> 3, c = cid & 7;
      *(bf16x8*)&Vs[d][c * 8] = *(const bf16x8*)(Vg + (size_t)d * SEQ + kt * 64 + c * 8);
    }
    __syncthreads();

    // ---- S = Q K^T (16q x 64k per wave) ----
    f32x4 sacc[4];
#pragma unroll
    for (int f = 0; f < 4; ++f) {
      sacc[f] = fzero;
#pragma unroll
      for (int ks = 0; ks < 4; ++ks) {
        bf16x8 kf = *(const bf16x8*)&Ks[f * 16 + lr][ks * 32 + lg * 8];
        sacc[f] = MFMA_BF16(qf[ks], kf, sacc[f]);
      }
    }

    // ---- online softmax (C-layout: row = lg*4+j, col = lr) ----
    unsigned long long mw[4];
#pragma unroll
    for (int j = 0; j < 4; ++j) mw[j] = mb[(size_t)(q0 + w * 16 + lg * 4 + j) * 32 + kt];

    float xs[4][4];
    float mt[4] = {-3.0e38f, -3.0e38f, -3.0e38f, -3.0e38f};
#pragma unroll
    for (int f = 0; f < 4; ++f)
#pragma unroll
      for (int j = 0; j < 4; ++j) {
        float x = sacc[f][j] * scale;
        int kk = f * 16 + lr;
        x = ((mw[j] >> kk) & 1ull) ? x : -1.0e7f;
        xs[f][j] = x;
        mt[j] = fmaxf(mt[j], x);
      }
#pragma unroll
    for (int off = 1; off < 16; off <<= 1)
#pragma unroll
      for (int j = 0; j < 4; ++j) mt[j] = fmaxf(mt[j], __shfl_xor(mt[j], off, 16));

    float alpha[4], psum[4];
#pragma unroll
    for (int j = 0; j < 4; ++j) {
      float mn = fmaxf(mrun[j], mt[j]);
      alpha[j] = exp2f((mrun[j] - mn) * L2E);
      mrun[j] = mn;
      psum[j] = 0.f;
    }
    float pb[4][4];
#pragma unroll
    for (int f = 0; f < 4; ++f)
#pragma unroll
      for (int j = 0; j < 4; ++j) {
        float p = exp2f((xs[f][j] - mrun[j]) * L2E);
        pb[f][j] = p;
        psum[j] += p;
      }
#pragma unroll
    for (int off = 1; off < 16; off <<= 1)
#pragma unroll
      for (int j = 0; j < 4; ++j) psum[j] += __shfl_xor(psum[j], off, 16);
#pragma unroll
    for (int j = 0; j < 4; ++j) lrun[j] = lrun[j] * alpha[j] + psum[j];
#pragma unroll
    for (int df = 0; df < 8; ++df)
#pragma unroll
      for (int j = 0; j < 4; ++j) oacc[df][j] *= alpha[j];

    // ---- P -> LDS (per-wave), then PV ----
#pragma unroll
    for (int f = 0; f < 4; ++f)
#pragma unroll
      for (int j = 0; j < 4; ++j) Ps[w][lg * 4 + j][f * 16 + lr] = (bf16)pb[f][j];

    bf16x8 pA[2];
#pragma unroll
    for (int ks = 0; ks < 2; ++ks) pA[ks] = *(const bf16x8*)&Ps[w][lr][ks * 32 + lg * 8];
#pragma unroll
    for (int df = 0; df < 8; ++df) {
#pragma unroll
      for (int ks = 0; ks < 2; ++ks) {
        bf16x8 vB = *(const bf16x8*)&Vs[df * 16 + lr][ks * 32 + lg * 8];
        oacc[df] = MFMA_BF16(pA[ks], vB, oacc[df]);
      }
    }
    __syncthreads();
  }

  // ---- epilogue: O /= l, f32 out[n][s][h*128+d] ----
#pragma unroll
  for (int df = 0; df < 8; ++df)
#pragma unroll
    for (int j = 0; j < 4; ++j) {
      float v = oacc[df][j] / lrun[j];
      out[(size_t)(n * SEQ + qrow + lg * 4 + j) * ODIM + h * HD + df * 16 + lr] = v;
    }
}

extern "C" void kernel_launch(void* const* d_in, const int* in_sizes, int n_in,
                              void* d_out, int out_size, void* d_ws, size_t ws_size,
                              hipStream_t stream) {
  const float* q   = (const float*)d_in[0];
  const float* k   = (const float*)d_in[1];
  const float* v   = (const float*)d_in[2];
  const int*  mask = (const int*)d_in[3];
  const float* Wq  = (const float*)d_in[4];
  const float* bq  = (const float*)d_in[5];
  const float* Wk  = (const float*)d_in[6];
  const float* bk  = (const float*)d_in[7];
  const float* Wv  = (const float*)d_in[8];
  const float* bv  = (const float*)d_in[9];
  float* out = (float*)d_out;

  char* ws = (char*)d_ws;
  const size_t PLANE = (size_t)4096 * 2048 * sizeof(bf16);  // 16 MiB
  bf16* Qb = (bf16*)ws;
  bf16* Kb = (bf16*)(ws + PLANE);
  bf16* Vt = (bf16*)(ws + 2 * PLANE);
  unsigned long long* mb = (unsigned long long*)(ws + 3 * PLANE);

  build_maskbits_k<<<256, 256, 0, stream>>>(mask, mb);
  proj_gemm_k<<<dim3(16, 32), 256, 0, stream>>>(q, Wq, bq, Qb, nullptr, 0);
  proj_gemm_k<<<dim3(16, 32), 256, 0, stream>>>(k, Wk, bk, Kb, nullptr, 0);
  proj_gemm_k<<<dim3(16, 32), 256, 0, stream>>>(v, Wv, bv, nullptr, Vt, 1);
  attn_k<<<dim3(SEQ / 64, 32), 256, 0, stream>>>(Qb, Kb, Vt, mb, out);
}

// Round 2
// 265.430 us; speedup vs baseline: 1.7695x; 1.7695x over previous
//
#include <hip/hip_runtime.h>

typedef __bf16 bf16;
typedef __bf16 bf16x8 __attribute__((ext_vector_type(8)));
typedef __bf16 bf16x4 __attribute__((ext_vector_type(4)));
typedef float f32x4 __attribute__((ext_vector_type(4)));

#define MFMA_BF16(A, B, C) __builtin_amdgcn_mfma_f32_16x16x32_bf16((A), (B), (C), 0, 0, 0)

#define EMB 1024
#define ODIM 2048
#define SEQ 2048
#define HEADS 16
#define HD 128

// ---------------- mask bit-pack: mask (1,S,S) int32 -> mb[q][kt] uint64 ----------------
__global__ __launch_bounds__(256) void build_maskbits_k(const int* __restrict__ mask,
                                                        unsigned long long* __restrict__ mb) {
  int w = blockIdx.x * 256 + threadIdx.x;  // 0..65535 : q*32 + chunk
  int q = w >> 5, c = w & 31;
  const int4* m4 = reinterpret_cast<const int4*>(mask + (size_t)q * SEQ + c * 64);
  unsigned long long bits = 0ull;
#pragma unroll
  for (int i = 0; i < 16; ++i) {
    int4 v = m4[i];
    if (v.x) bits |= 1ull << (i * 4 + 0);
    if (v.y) bits |= 1ull << (i * 4 + 1);
    if (v.z) bits |= 1ull << (i * 4 + 2);
    if (v.w) bits |= 1ull << (i * 4 + 3);
  }
  mb[w] = bits;
}

// ---------------- projection GEMM: out = relu(X (4096x1024) * W^T (2048x1024) + b) ----------------
// vmode==0: write bf16 to outN[row][col] (row-major 4096x2048)
// vmode==1: write bf16 transposed per head to outT[((n*16+h)*128+d)*2048 + s]
__global__ __launch_bounds__(256) void proj_gemm_k(const float* __restrict__ X,
                                                   const float* __restrict__ W,
                                                   const float* __restrict__ bias,
                                                   bf16* __restrict__ outN,
                                                   bf16* __restrict__ outT,
                                                   int vmode) {
  __shared__ union {
    struct { bf16 A[128][40]; bf16 B[128][40]; } s;  // +8 pad: 2-way conflicts max (free)
    bf16 C[128][136];                                // transpose buffer (epilogue only)
  } sm;

  const int t = threadIdx.x;
  const int lane = t & 63;
  const int wid = t >> 6;
  const int wm = wid >> 1, wn = wid & 1;
  const int lr = lane & 15, lg = lane >> 4;
  const int m0 = blockIdx.y * 128;
  const int n0 = blockIdx.x * 128;
  const int sr = t >> 1, sh = (t & 1) * 16;  // staging: 2 threads per row, 16 f32 each

  const f32x4 fzero = {0.f, 0.f, 0.f, 0.f};
  f32x4 acc[4][4];
#pragma unroll
  for (int i = 0; i < 4; ++i)
#pragma unroll
    for (int j = 0; j < 4; ++j) acc[i][j] = fzero;

  const float* Xr = X + (size_t)(m0 + sr) * EMB + sh;
  const float* Wr = W + (size_t)(n0 + sr) * EMB + sh;

  // async-split staging: issue tile k+1 loads while MFMAing tile k
  float4 ar[4], br[4];
  {
    const float4* pa = reinterpret_cast<const float4*>(Xr);
    const float4* pb = reinterpret_cast<const float4*>(Wr);
#pragma unroll
    for (int i = 0; i < 4; ++i) { ar[i] = pa[i]; br[i] = pb[i]; }
  }

  for (int k0 = 0; k0 < EMB; k0 += 32) {
    {
      bf16x8 v0, v1, w0, w1;
      v0[0] = (bf16)ar[0].x; v0[1] = (bf16)ar[0].y; v0[2] = (bf16)ar[0].z; v0[3] = (bf16)ar[0].w;
      v0[4] = (bf16)ar[1].x; v0[5] = (bf16)ar[1].y; v0[6] = (bf16)ar[1].z; v0[7] = (bf16)ar[1].w;
      v1[0] = (bf16)ar[2].x; v1[1] = (bf16)ar[2].y; v1[2] = (bf16)ar[2].z; v1[3] = (bf16)ar[2].w;
      v1[4] = (bf16)ar[3].x; v1[5] = (bf16)ar[3].y; v1[6] = (bf16)ar[3].z; v1[7] = (bf16)ar[3].w;
      w0[0] = (bf16)br[0].x; w0[1] = (bf16)br[0].y; w0[2] = (bf16)br[0].z; w0[3] = (bf16)br[0].w;
      w0[4] = (bf16)br[1].x; w0[5] = (bf16)br[1].y; w0[6] = (bf16)br[1].z; w0[7] = (bf16)br[1].w;
      w1[0] = (bf16)br[2].x; w1[1] = (bf16)br[2].y; w1[2] = (bf16)br[2].z; w1[3] = (bf16)br[2].w;
      w1[4] = (bf16)br[3].x; w1[5] = (bf16)br[3].y; w1[6] = (bf16)br[3].z; w1[7] = (bf16)br[3].w;
      *(bf16x8*)&sm.s.A[sr][sh] = v0;
      *(bf16x8*)&sm.s.A[sr][sh + 8] = v1;
      *(bf16x8*)&sm.s.B[sr][sh] = w0;
      *(bf16x8*)&sm.s.B[sr][sh + 8] = w1;
    }
    __syncthreads();
    if (k0 + 32 < EMB) {
      const float4* pa = reinterpret_cast<const float4*>(Xr + k0 + 32);
      const float4* pb = reinterpret_cast<const float4*>(Wr + k0 + 32);
#pragma unroll
      for (int i = 0; i < 4; ++i) { ar[i] = pa[i]; br[i] = pb[i]; }
    }
    bf16x8 af[4], bfr[4];
#pragma unroll
    for (int i = 0; i < 4; ++i) af[i] = *(const bf16x8*)&sm.s.A[wm * 64 + i * 16 + lr][lg * 8];
#pragma unroll
    for (int i = 0; i < 4; ++i) bfr[i] = *(const bf16x8*)&sm.s.B[wn * 64 + i * 16 + lr][lg * 8];
#pragma unroll
    for (int mi = 0; mi < 4; ++mi)
#pragma unroll
      for (int ni = 0; ni < 4; ++ni)
        acc[mi][ni] = MFMA_BF16(af[mi], bfr[ni], acc[mi][ni]);
    __syncthreads();
  }

  float bv_[4];
#pragma unroll
  for (int ni = 0; ni < 4; ++ni) bv_[ni] = bias[n0 + wn * 64 + ni * 16 + lr];

  if (!vmode) {
#pragma unroll
    for (int mi = 0; mi < 4; ++mi)
#pragma unroll
      for (int ni = 0; ni < 4; ++ni)
#pragma unroll
        for (int j = 0; j < 4; ++j) {
          float v = fmaxf(acc[mi][ni][j] + bv_[ni], 0.f);
          int row = m0 + wm * 64 + mi * 16 + lg * 4 + j;
          int col = n0 + wn * 64 + ni * 16 + lr;
          outN[(size_t)row * ODIM + col] = (bf16)v;
        }
  } else {
    // transpose tile through LDS, then coalesced row writes into Vt[n][h][d][s]
#pragma unroll
    for (int mi = 0; mi < 4; ++mi)
#pragma unroll
      for (int ni = 0; ni < 4; ++ni)
#pragma unroll
        for (int j = 0; j < 4; ++j) {
          float v = fmaxf(acc[mi][ni][j] + bv_[ni], 0.f);
          int rit = wm * 64 + mi * 16 + lg * 4 + j;  // s within tile
          int cit = wn * 64 + ni * 16 + lr;          // d within tile
          sm.C[cit][rit] = (bf16)v;
        }
    __syncthreads();
    const int n = m0 >> 11;
    const int s0 = m0 & (SEQ - 1);
    const int h = blockIdx.x;  // n0/128 == head (BN==HD)
    bf16* base = outT + ((size_t)(n * HEADS + h) * HD) * SEQ + s0;
#pragma unroll
    for (int i = 0; i < 8; ++i) {
      int cid = i * 256 + t;
      int d = cid >> 4, c = cid & 15;
      *(bf16x8*)(base + (size_t)d * SEQ + c * 8) = *(const bf16x8*)&sm.C[d][c * 8];
    }
  }
}

// ---------------- flash attention (swapped-operand form) ----------------
// grid: x = q-tile (S/64), y = n*16+h ; 256 threads = 4 waves, 16 q-rows per wave
// QK^T computed as mfma(K,Q) -> S^T: col=q=lane&15 (lane-local softmax)
// PV  computed as mfma(V^T,P) -> O^T[d][q]: col=q=lane&15 (lane-local rescale/divide)
__global__ __launch_bounds__(256) void attn_k(const bf16* __restrict__ Qb,
                                              const bf16* __restrict__ Kb,
                                              const bf16* __restrict__ Vt,
                                              const unsigned long long* __restrict__ mb,
                                              float* __restrict__ out) {
  __shared__ bf16 Ks[64][136];    // K tile: [key][d], +8 pad
  __shared__ bf16 Vs[128][72];    // V^T tile: [d][s], +8 pad
  __shared__ bf16 Ps[4][16][72];  // per-wave P: [q][k], +8 pad

  const int t = threadIdx.x;
  const int lane = t & 63;
  const int w = t >> 6;
  const int lr = lane & 15, lg = lane >> 4;
  const int nh = blockIdx.y;
  const int n = nh >> 4, h = nh & 15;
  const int q0 = blockIdx.x * 64;
  const int qrow = q0 + w * 16;

  // Q fragments (B-operand: col=q=lane&15, k=d)
  bf16x8 qf[4];
  {
    const bf16* qp = Qb + (size_t)(n * SEQ + qrow + lr) * ODIM + h * HD + lg * 8;
#pragma unroll
    for (int ks = 0; ks < 4; ++ks) qf[ks] = *(const bf16x8*)(qp + ks * 32);
  }

  const bf16* Kg = Kb + (size_t)(n * SEQ) * ODIM + h * HD;
  const bf16* Vg = Vt + (size_t)nh * HD * SEQ;

  // staging addresses (reg-staged, async-split)
  const int rK = t >> 4, cK = t & 15;  // K: 16 threads/row, 8 bf16 each
  const int dV = t >> 3, cV = t & 7;   // V^T: 8 threads/row
  const bf16* kgp = Kg + (size_t)rK * ODIM + cK * 8;
  const bf16* vgp = Vg + (size_t)dV * SEQ + cV * 8;

  bf16x8 kreg[4], vreg[4];
#pragma unroll
  for (int i = 0; i < 4; ++i) kreg[i] = *(const bf16x8*)(kgp + (size_t)i * 16 * ODIM);
#pragma unroll
  for (int i = 0; i < 4; ++i) vreg[i] = *(const bf16x8*)(vgp + (size_t)i * 32 * SEQ);

  const f32x4 fzero = {0.f, 0.f, 0.f, 0.f};
  f32x4 oacc[8];  // O^T frags: oacc[df][j] = O[d=df*16+lg*4+j][q=lr]
#pragma unroll
  for (int i = 0; i < 8; ++i) oacc[i] = fzero;
  float mrun = -3.0e38f, lrun = 0.f;  // per-lane (q = qrow + lr)

  const float scale = 0.08838834764831845f;  // 1/sqrt(128)
  const float L2E = 1.4426950408889634f;

  for (int kt = 0; kt < SEQ / 64; ++kt) {
    // ---- write staged regs (tile kt) to LDS ----
#pragma unroll
    for (int i = 0; i < 4; ++i) *(bf16x8*)&Ks[rK + i * 16][cK * 8] = kreg[i];
#pragma unroll
    for (int i = 0; i < 4; ++i) *(bf16x8*)&Vs[dV + i * 32][cV * 8] = vreg[i];
    __syncthreads();

    // ---- issue tile kt+1 loads (latency hides under compute below) ----
    if (kt + 1 < SEQ / 64) {
      const bf16* kn = kgp + (size_t)(kt + 1) * 64 * ODIM;
      const bf16* vn = vgp + (size_t)(kt + 1) * 64;
#pragma unroll
      for (int i = 0; i < 4; ++i) kreg[i] = *(const bf16x8*)(kn + (size_t)i * 16 * ODIM);
#pragma unroll
      for (int i = 0; i < 4; ++i) vreg[i] = *(const bf16x8*)(vn + (size_t)i * 32 * SEQ);
    }

    // ---- S^T = K Q^T : row=k=f*16+lg*4+j, col=q=lr ----
    f32x4 sacc[4];
#pragma unroll
    for (int f = 0; f < 4; ++f) {
      sacc[f] = fzero;
#pragma unroll
      for (int ks = 0; ks < 4; ++ks) {
        bf16x8 kf = *(const bf16x8*)&Ks[f * 16 + lr][ks * 32 + lg * 8];
        sacc[f] = MFMA_BF16(kf, qf[ks], sacc[f]);
      }
    }

    // ---- lane-local online softmax ----
    unsigned long long mw = mb[(size_t)(qrow + lr) * 32 + kt];
    float xs[4][4];
    float mt = -3.0e38f;
#pragma unroll
    for (int f = 0; f < 4; ++f)
#pragma unroll
      for (int j = 0; j < 4; ++j) {
        int kk = f * 16 + lg * 4 + j;
        float x = ((mw >> kk) & 1ull) ? sacc[f][j] * scale : -1.0e7f;
        xs[f][j] = x;
        mt = fmaxf(mt, x);
      }
    mt = fmaxf(mt, __shfl_xor(mt, 16));
    mt = fmaxf(mt, __shfl_xor(mt, 32));

    // defer-max (T13): only rescale when the max moved by >8
    if (!__all(mt <= mrun + 8.0f)) {
      float mnew = fmaxf(mrun, mt);
      float alpha = exp2f((mrun - mnew) * L2E);
      mrun = mnew;
      lrun *= alpha;
#pragma unroll
      for (int df = 0; df < 8; ++df)
#pragma unroll
        for (int j = 0; j < 4; ++j) oacc[df][j] *= alpha;
    }

    float psum = 0.f;
#pragma unroll
    for (int f = 0; f < 4; ++f) {
      bf16x4 pw;
#pragma unroll
      for (int j = 0; j < 4; ++j) {
        float p = exp2f((xs[f][j] - mrun) * L2E);
        psum += p;
        pw[j] = (bf16)p;
      }
      *(bf16x4*)&Ps[w][lr][f * 16 + lg * 4] = pw;  // k-contiguous b64 write
    }
    psum += __shfl_xor(psum, 16);
    psum += __shfl_xor(psum, 32);
    lrun += psum;

    // ---- O^T += V^T P : A=V^T frag (row=d), B=P frag (col=q) ----
    bf16x8 pB0 = *(const bf16x8*)&Ps[w][lr][lg * 8];
    bf16x8 pB1 = *(const bf16x8*)&Ps[w][lr][32 + lg * 8];
#pragma unroll
    for (int df = 0; df < 8; ++df) {
      bf16x8 v0 = *(const bf16x8*)&Vs[df * 16 + lr][lg * 8];
      bf16x8 v1 = *(const bf16x8*)&Vs[df * 16 + lr][32 + lg * 8];
      oacc[df] = MFMA_BF16(v0, pB0, oacc[df]);
      oacc[df] = MFMA_BF16(v1, pB1, oacc[df]);
    }
    __syncthreads();
  }

  // ---- epilogue: O /= l ; float4 stores ----
  float inv = 1.0f / lrun;
  float* obase = out + (size_t)(n * SEQ + qrow + lr) * ODIM + h * HD;
#pragma unroll
  for (int df = 0; df < 8; ++df) {
    f32x4 o;
#pragma unroll
    for (int j = 0; j < 4; ++j) o[j] = oacc[df][j] * inv;
    *(f32x4*)(obase + df * 16 + lg * 4) = o;
  }
}

extern "C" void kernel_launch(void* const* d_in, const int* in_sizes, int n_in,
                              void* d_out, int out_size, void* d_ws, size_t ws_size,
                              hipStream_t stream) {
  const float* q   = (const float*)d_in[0];
  const float* k   = (const float*)d_in[1];
  const float* v   = (const float*)d_in[2];
  const int*  mask = (const int*)d_in[3];
  const float* Wq  = (const float*)d_in[4];
  const float* bq  = (const float*)d_in[5];
  const float* Wk  = (const float*)d_in[6];
  const float* bk  = (const float*)d_in[7];
  const float* Wv  = (const float*)d_in[8];
  const float* bv  = (const float*)d_in[9];
  float* out = (float*)d_out;

  char* ws = (char*)d_ws;
  const size_t PLANE = (size_t)4096 * 2048 * sizeof(bf16);  // 16 MiB
  bf16* Qb = (bf16*)ws;
  bf16* Kb = (bf16*)(ws + PLANE);
  bf16* Vt = (bf16*)(ws + 2 * PLANE);
  unsigned long long* mb = (unsigned long long*)(ws + 3 * PLANE);

  build_maskbits_k<<<256, 256, 0, stream>>>(mask, mb);
  proj_gemm_k<<<dim3(16, 32), 256, 0, stream>>>(q, Wq, bq, Qb, nullptr, 0);
  proj_gemm_k<<<dim3(16, 32), 256, 0, stream>>>(k, Wk, bk, Kb, nullptr, 0);
  proj_gemm_k<<<dim3(16, 32), 256, 0, stream>>>(v, Wv, bv, nullptr, Vt, 1);
  attn_k<<<dim3(SEQ / 64, 32), 256, 0, stream>>>(Qb, Kb, Vt, mb, out);
}